// Round 9
// baseline (64.957 us; speedup 1.0000x reference)
//
#include <hip/hip_runtime.h>
#include <hip/hip_bf16.h>

typedef __attribute__((ext_vector_type(8))) short short8;
typedef __attribute__((ext_vector_type(4))) float f32x4;
typedef __attribute__((ext_vector_type(4))) int   int4v;

#define IN_F   4096
#define OUT_F  11008
#define COLS   128               // out-cols per block
#define KSPLIT 16
#define KPART  (IN_F / KSPLIT)   // 256 k per block
#define BK     64
#define NIT    (KPART / BK)      // 4 chunks
#define DEPTH  2                 // LDS ring slots (stage-ahead 1, vmcnt(5))

// f32 -> bf16 round-to-nearest-even
__device__ __forceinline__ short bf16_rne(float f) {
    unsigned u = __builtin_bit_cast(unsigned, f);
    u += 0x7FFFu + ((u >> 16) & 1u);
    return (short)(u >> 16);
}

__device__ __forceinline__ void gld16(const void* g, void* l) {
    __builtin_amdgcn_global_load_lds(
        (const __attribute__((address_space(1))) unsigned int*)g,
        (__attribute__((address_space(3))) unsigned int*)l,
        16, 0, 0);
}

// dequant 8 ints -> short8 bf16 (exact: values in [-3,123])
__device__ __forceinline__ short8 deq8(int4v q0, int4v q1, int zp) {
    short8 r;
#pragma unroll
    for (int j = 0; j < 4; ++j) {
        r[j]     = (short)(__builtin_bit_cast(unsigned, (float)(q0[j] - zp)) >> 16);
        r[j + 4] = (short)(__builtin_bit_cast(unsigned, (float)(q1[j] - zp)) >> 16);
    }
    return r;
}

// ---------- prep: X f32 -> bf16 [64][4096] in d_ws ----------
__global__ __launch_bounds__(256)
void xcast(const float* __restrict__ x, unsigned short* __restrict__ xb) {
    const int i = (blockIdx.x * 256 + threadIdx.x) * 8;
    f32x4 a = *(const f32x4*)(x + i);
    f32x4 b = *(const f32x4*)(x + i + 4);
    short8 o;
#pragma unroll
    for (int j = 0; j < 4; ++j) { o[j] = bf16_rne(a[j]); o[j + 4] = bf16_rne(b[j]); }
    *(short8*)(xb + i) = o;
}

// ---------- main GEMM: 128 cols x 64 tokens, 8 waves own 16-col slices -------
// Stage chunk IT into ring slot IT&1: W 128x64 int32 (32KB, 4 gld/thr),
// X 64x64 bf16 (8KB, 1 gld/thr). Sources pre-swizzled (chunk ^ row&7),
// LDS dest linear (rule #21). 5 vmem instr per thread per stage.
#define STAGE(IT) do {                                                        \
    const int _s = (IT) & (DEPTH - 1);                                        \
    const int* _wsi = wsrc + (size_t)(IT) * BK;                               \
    gld16(_wsi,             (char*)wt[_s] + tid * 16);                        \
    gld16(_wsi + 32 * IN_F, (char*)wt[_s] + 8192  + tid * 16);                \
    gld16(_wsi + 64 * IN_F, (char*)wt[_s] + 16384 + tid * 16);                \
    gld16(_wsi + 96 * IN_F, (char*)wt[_s] + 24576 + tid * 16);                \
    gld16(xsrc + (size_t)(IT) * BK, (char*)xt[_s] + tid * 16);                \
} while (0)

// One chunk (BK=64): dequant own 16-col W slice once (2 k-step B-frags),
// then 4 token-groups x 2 k-steps = 8 MFMA.  (r6/r8-verbatim)
#define COMPUTE(S) do {                                                       \
    const char* _wb = (const char*)wt[S] + wrow_off;                          \
    int4v _q00 = *(const int4v*)(_wb + cw00);                                 \
    int4v _q01 = *(const int4v*)(_wb + cw01);                                 \
    int4v _q10 = *(const int4v*)(_wb + cw10);                                 \
    int4v _q11 = *(const int4v*)(_wb + cw11);                                 \
    short8 _B0 = deq8(_q00, _q01, zp);                                        \
    short8 _B1 = deq8(_q10, _q11, zp);                                        \
    const char* _xb = (const char*)xt[S] + arow;                              \
    short8 _a;                                                                \
    _a = *(const short8*)(_xb +        ca0);                                  \
    acc0 = __builtin_amdgcn_mfma_f32_16x16x32_bf16(_a, _B0, acc0, 0, 0, 0);   \
    _a = *(const short8*)(_xb +        ca1);                                  \
    acc0 = __builtin_amdgcn_mfma_f32_16x16x32_bf16(_a, _B1, acc0, 0, 0, 0);   \
    _a = *(const short8*)(_xb + 2048 + ca0);                                  \
    acc1 = __builtin_amdgcn_mfma_f32_16x16x32_bf16(_a, _B0, acc1, 0, 0, 0);   \
    _a = *(const short8*)(_xb + 2048 + ca1);                                  \
    acc1 = __builtin_amdgcn_mfma_f32_16x16x32_bf16(_a, _B1, acc1, 0, 0, 0);   \
    _a = *(const short8*)(_xb + 4096 + ca0);                                  \
    acc2 = __builtin_amdgcn_mfma_f32_16x16x32_bf16(_a, _B0, acc2, 0, 0, 0);   \
    _a = *(const short8*)(_xb + 4096 + ca1);                                  \
    acc2 = __builtin_amdgcn_mfma_f32_16x16x32_bf16(_a, _B1, acc2, 0, 0, 0);   \
    _a = *(const short8*)(_xb + 6144 + ca0);                                  \
    acc3 = __builtin_amdgcn_mfma_f32_16x16x32_bf16(_a, _B0, acc3, 0, 0, 0);   \
    _a = *(const short8*)(_xb + 6144 + ca1);                                  \
    acc3 = __builtin_amdgcn_mfma_f32_16x16x32_bf16(_a, _B1, acc3, 0, 0, 0);   \
} while (0)

__global__ __launch_bounds__(512, 4)
void qlin9(const unsigned short* __restrict__ xb, const int* __restrict__ w,
           const float* __restrict__ scale_p, const int* __restrict__ zp_p,
           const float* __restrict__ bias, float* __restrict__ out)
{
    __shared__ __align__(16) int            wt[DEPTH][COLS * BK]; // 2 x 32KB
    __shared__ __align__(16) unsigned short xt[DEPTH][64 * BK];   // 2 x 8KB  (80KB -> 2 blk/CU)

    const int tid  = threadIdx.x;
    const int lane = tid & 63;
    const int wv   = tid >> 6;      // wave 0..7 -> 16-col slice
    const int l15  = lane & 15;
    const int lg   = lane >> 4;

    const int ob = blockIdx.x >> 4;          // 86 col-tiles
    const int kh = blockIdx.x & 15;          // K sixteenth
    const int o0 = ob * COLS;
    const int kb = kh * KPART;

    const int   zp    = zp_p[0];
    const float scale = scale_p[0];

    // W staging: thread t -> rows (t>>4)+{0,32,64,96}, chunk (t&15)^(row&7).
    // (row+32k)&7 == row&7, so one swizzled base serves all 4 slices.
    const int wr = tid >> 4;                 // 0..31
    const int wc = (tid & 15) ^ (wr & 7);
    const int* wsrc = w + (size_t)(o0 + wr) * IN_F + kb + wc * 4;

    // X staging: thread t -> row t>>3 (0..63), chunk (t&7)^(row&7).
    const int xr = tid >> 3;
    const int xc = (tid & 7) ^ (xr & 7);
    const unsigned short* xsrc = xb + (size_t)xr * IN_F + kb + xc * 8;

    // Read-side swizzle (r6-verbatim): B row = wv*16+l15, A row = g*16+l15.
    const int rswz = l15 & 7;
    const int wrow_off = (wv * 16 + l15) * 256;          // W LDS row (256B pitch)
    const int cw00 = ((lg * 2    ) ^ rswz) * 16;
    const int cw01 = ((lg * 2 + 1) ^ rswz) * 16;
    const int cw10 = ((8 + lg * 2    ) ^ rswz) * 16;
    const int cw11 = ((8 + lg * 2 + 1) ^ rswz) * 16;
    const int arow = l15 * 128;                          // X LDS row (128B pitch)
    const int ca0  = ((lg    ) ^ rswz) * 16;
    const int ca1  = ((4 + lg) ^ rswz) * 16;

    f32x4 acc0 = {0.f, 0.f, 0.f, 0.f};
    f32x4 acc1 = {0.f, 0.f, 0.f, 0.f};
    f32x4 acc2 = {0.f, 0.f, 0.f, 0.f};
    f32x4 acc3 = {0.f, 0.f, 0.f, 0.f};

    // Prologue: 2 chunks in flight (10 vmem instrs/thread)
    STAGE(0);
    STAGE(1);

    // Window it: vmcnt(5) -> chunk it landed, chunk it+1 stays in flight;
    // barrier (cross-wave visibility); compute; barrier (seal slot it&1);
    // stage it+2 into slot it&1.  Last window: vmcnt(0).
#pragma unroll
    for (int it = 0; it < NIT; ++it) {
        if (it < NIT - 1) asm volatile("s_waitcnt vmcnt(5)" ::: "memory");
        else              asm volatile("s_waitcnt vmcnt(0)" ::: "memory");
        __builtin_amdgcn_s_barrier();
        COMPUTE(it & 1);
        if (it + 2 < NIT) {
            __builtin_amdgcn_s_barrier();
            STAGE(it + 2);
        }
    }

    // Epilogue: D col = lane&15, row = (lane>>4)*4 + reg. K-split partials
    // atomically accumulate onto memset-zeroed out; kh==0 blocks fold bias in.
    {
        const int o = o0 + wv * 16 + l15;
        const float bb = (kh == 0) ? bias[o] : 0.0f;
        float* op = out + o;
#pragma unroll
        for (int r = 0; r < 4; ++r) {
            const int tr = lg * 4 + r;
            unsafeAtomicAdd(op + (size_t)(tr     ) * OUT_F, scale * acc0[r] + bb);
            unsafeAtomicAdd(op + (size_t)(tr + 16) * OUT_F, scale * acc1[r] + bb);
            unsafeAtomicAdd(op + (size_t)(tr + 32) * OUT_F, scale * acc2[r] + bb);
            unsafeAtomicAdd(op + (size_t)(tr + 48) * OUT_F, scale * acc3[r] + bb);
        }
    }
}

extern "C" void kernel_launch(void* const* d_in, const int* in_sizes, int n_in,
                              void* d_out, int out_size, void* d_ws, size_t ws_size,
                              hipStream_t stream) {
    const float* x     = (const float*)d_in[0];
    const int*   w     = (const int*)d_in[1];
    const float* scale = (const float*)d_in[2];
    const int*   zp    = (const int*)d_in[3];
    const float* bias  = (const float*)d_in[4];
    float*       out   = (float*)d_out;
    unsigned short* xbf = (unsigned short*)d_ws;   // 512 KB of d_ws

    // zero the accumulation target (graph-capturable memset node)
    hipMemsetAsync(d_out, 0, (size_t)out_size * sizeof(float), stream);
    xcast<<<dim3(128), dim3(256), 0, stream>>>(x, xbf);
    qlin9<<<dim3((OUT_F / COLS) * KSPLIT), dim3(512), 0, stream>>>(xbf, w, scale, zp, bias, out);
}

// Round 11
// 49.414 us; speedup vs baseline: 1.3146x; 1.3146x over previous
//
#include <hip/hip_runtime.h>
#include <hip/hip_bf16.h>

typedef __attribute__((ext_vector_type(8))) short short8;
typedef __attribute__((ext_vector_type(4))) float f32x4;
typedef __attribute__((ext_vector_type(4))) int   int4v;

#define IN_F   4096
#define OUT_F  11008
#define COLS   128               // out-cols per block (8 waves x 16-col slices)
#define KSPLIT 8
#define KPART  (IN_F / KSPLIT)   // 512 k per block
#define BK     64
#define NIT    (KPART / BK)      // 8 chunks
#define DEPTH  2                 // X LDS ring slots

// f32 -> bf16 round-to-nearest-even
__device__ __forceinline__ short bf16_rne(float f) {
    unsigned u = __builtin_bit_cast(unsigned, f);
    u += 0x7FFFu + ((u >> 16) & 1u);
    return (short)(u >> 16);
}

__device__ __forceinline__ void gld16(const void* g, void* l) {
    __builtin_amdgcn_global_load_lds(
        (const __attribute__((address_space(1))) unsigned int*)g,
        (__attribute__((address_space(3))) unsigned int*)l,
        16, 0, 0);
}

// dequant 8 ints -> short8 bf16 (exact: values in [-3,123])
__device__ __forceinline__ short8 deq8(int4v q0, int4v q1, int zp) {
    short8 r;
#pragma unroll
    for (int j = 0; j < 4; ++j) {
        r[j]     = (short)(__builtin_bit_cast(unsigned, (float)(q0[j] - zp)) >> 16);
        r[j + 4] = (short)(__builtin_bit_cast(unsigned, (float)(q1[j] - zp)) >> 16);
    }
    return r;
}

// ---------- prep: X f32->bf16 cast (blocks 0..127) + bias-init of out (all) --
__global__ __launch_bounds__(256)
void prep(const float* __restrict__ x, const float* __restrict__ bias,
          unsigned short* __restrict__ xb, float* __restrict__ out) {
    const unsigned cid = blockIdx.x * 256 + threadIdx.x;
    if (blockIdx.x < 128) {
        const int i = cid * 8;
        f32x4 a = *(const f32x4*)(x + i);
        f32x4 b = *(const f32x4*)(x + i + 4);
        short8 o;
#pragma unroll
        for (int j = 0; j < 4; ++j) { o[j] = bf16_rne(a[j]); o[j + 4] = bf16_rne(b[j]); }
        *(short8*)(xb + i) = o;
    }
    const unsigned row = cid / (OUT_F / 8);
    const unsigned o   = (cid - row * (OUT_F / 8)) * 8;
    f32x4 b0 = *(const f32x4*)(bias + o);
    f32x4 b1 = *(const f32x4*)(bias + o + 4);
    float* dst = out + (size_t)row * OUT_F + o;
    *(f32x4*)dst = b0;
    *(f32x4*)(dst + 4) = b1;
}

// ---------- main GEMM: W -> registers (wave-exclusive rows), X -> LDS ring ---
// W chunk IT -> named register set S via pinned asm (issue order owns vmcnt).
// Lane (l15=col-in-slice, lg=kgroup): ints [lg*8..+7] (k-step0) at +0/+16B,
// ints [32+lg*8..+7] (k-step1) at +128/+144B of its row.
#define WLOAD(IT, S) do {                                                     \
    const int* _p = wlane + (size_t)(IT) * BK;                                \
    asm volatile("global_load_dwordx4 %0, %4, off\n\t"                        \
                 "global_load_dwordx4 %1, %4, off offset:16\n\t"              \
                 "global_load_dwordx4 %2, %4, off offset:128\n\t"             \
                 "global_load_dwordx4 %3, %4, off offset:144"                 \
        : "=&v"(qw##S##0), "=&v"(qw##S##1), "=&v"(qw##S##2), "=&v"(qw##S##3)  \
        : "v"(_p) : "memory");                                                \
} while (0)

#define WLOAD_ROT(IT) do {                                                    \
    const int _m = (IT) % 3;                                                  \
    if (_m == 0)      WLOAD(IT, A);                                           \
    else if (_m == 1) WLOAD(IT, B);                                           \
    else              WLOAD(IT, C);                                           \
} while (0)

// X chunk IT -> LDS ring slot IT&1 (1 gld16/thread, source pre-swizzled)
#define XSTAGE(IT) \
    gld16(xsrc + (size_t)(IT) * BK, (char*)xt[(IT) & (DEPTH - 1)] + tid * 16)

// One chunk: dequant own W regs (set S), 4 token-groups x 2 k-steps = 8 MFMA.
#define COMPUTE(S, SLOT) do {                                                 \
    short8 _B0 = deq8(qw##S##0, qw##S##1, zp);                                \
    short8 _B1 = deq8(qw##S##2, qw##S##3, zp);                                \
    const char* _xb = (const char*)xt[SLOT] + arow;                           \
    short8 _a;                                                                \
    _a = *(const short8*)(_xb +        ca0);                                  \
    acc0 = __builtin_amdgcn_mfma_f32_16x16x32_bf16(_a, _B0, acc0, 0, 0, 0);   \
    _a = *(const short8*)(_xb +        ca1);                                  \
    acc0 = __builtin_amdgcn_mfma_f32_16x16x32_bf16(_a, _B1, acc0, 0, 0, 0);   \
    _a = *(const short8*)(_xb + 2048 + ca0);                                  \
    acc1 = __builtin_amdgcn_mfma_f32_16x16x32_bf16(_a, _B0, acc1, 0, 0, 0);   \
    _a = *(const short8*)(_xb + 2048 + ca1);                                  \
    acc1 = __builtin_amdgcn_mfma_f32_16x16x32_bf16(_a, _B1, acc1, 0, 0, 0);   \
    _a = *(const short8*)(_xb + 4096 + ca0);                                  \
    acc2 = __builtin_amdgcn_mfma_f32_16x16x32_bf16(_a, _B0, acc2, 0, 0, 0);   \
    _a = *(const short8*)(_xb + 4096 + ca1);                                  \
    acc2 = __builtin_amdgcn_mfma_f32_16x16x32_bf16(_a, _B1, acc2, 0, 0, 0);   \
    _a = *(const short8*)(_xb + 6144 + ca0);                                  \
    acc3 = __builtin_amdgcn_mfma_f32_16x16x32_bf16(_a, _B0, acc3, 0, 0, 0);   \
    _a = *(const short8*)(_xb + 6144 + ca1);                                  \
    acc3 = __builtin_amdgcn_mfma_f32_16x16x32_bf16(_a, _B1, acc3, 0, 0, 0);   \
} while (0)

#define COMPUTE_ROT(IT) do {                                                  \
    const int _m = (IT) % 3;                                                  \
    if (_m == 0)      COMPUTE(A, (IT) & 1);                                   \
    else if (_m == 1) COMPUTE(B, (IT) & 1);                                   \
    else              COMPUTE(C, (IT) & 1);                                   \
} while (0)

__global__ __launch_bounds__(512, 4)
void qlin11(const unsigned short* __restrict__ xb, const int* __restrict__ w,
            const float* __restrict__ scale_p, const int* __restrict__ zp_p,
            float* __restrict__ out)
{
    __shared__ __align__(16) unsigned short xt[DEPTH][64 * BK];  // 2 x 8KB only

    const int tid  = threadIdx.x;
    const int lane = tid & 63;
    const int wv   = tid >> 6;      // wave 0..7 -> 16-col slice
    const int l15  = lane & 15;
    const int lg   = lane >> 4;

    const int ob = blockIdx.x >> 3;          // 86 col-tiles
    const int kh = blockIdx.x & 7;           // K eighth
    const int o0 = ob * COLS;
    const int kb = kh * KPART;

    const int   zp    = zp_p[0];
    const float scale = scale_p[0];

    // Per-lane W row pointer (wave-exclusive row: no LDS, no swizzle needed)
    const int* wlane = w + (size_t)(o0 + wv * 16 + l15) * IN_F + kb + lg * 8;

    // X staging: thread t -> row t>>3 (0..63), chunk (t&7)^(row&7)  (r8-verbatim)
    const int xr = tid >> 3;
    const int xc = (tid & 7) ^ (xr & 7);
    const unsigned short* xsrc = xb + (size_t)xr * IN_F + kb + xc * 8;

    // X read-side swizzle (r8-verbatim): A row = g*16+l15, 128B pitch.
    const int rswz = l15 & 7;
    const int arow = l15 * 128;
    const int ca0  = ((lg    ) ^ rswz) * 16;
    const int ca1  = ((4 + lg) ^ rswz) * 16;

    f32x4 acc0 = {0.f, 0.f, 0.f, 0.f};
    f32x4 acc1 = {0.f, 0.f, 0.f, 0.f};
    f32x4 acc2 = {0.f, 0.f, 0.f, 0.f};
    f32x4 acc3 = {0.f, 0.f, 0.f, 0.f};

    // W register triple-buffer: window it computes set it%3, prefetches
    // it+2 into (it+2)%3 == (it-1)%3 -> always the set consumed LAST window.
    int4v qwA0, qwA1, qwA2, qwA3;
    int4v qwB0, qwB1, qwB2, qwB3;
    int4v qwC0, qwC1, qwC2, qwC3;

    // Prologue queue (10 vmem ops/thread): [W0(4), X0(1), W1(4), X1(1)]
    WLOAD(0, A);
    XSTAGE(0);
    WLOAD(1, B);
    XSTAGE(1);

    // Window it: vmcnt(5) retires exactly {W(it), X(it)}; {W(it+1), X(it+1)}
    // stay in flight. sched_barrier fences deq/MFMA hoisting above the wait
    // (rule #18: asm-loaded regs have no compiler wait). Second barrier seals
    // X slot it&1 before XSTAGE(it+2) overwrites it.
#pragma unroll
    for (int it = 0; it < NIT; ++it) {
        if (it < NIT - 1) asm volatile("s_waitcnt vmcnt(5)" ::: "memory");
        else              asm volatile("s_waitcnt vmcnt(0)" ::: "memory");
        __builtin_amdgcn_s_barrier();
        __builtin_amdgcn_sched_barrier(0);
        if (it + 2 < NIT) WLOAD_ROT(it + 2);
        COMPUTE_ROT(it);
        if (it + 2 < NIT) {
            __builtin_amdgcn_s_barrier();
            XSTAGE(it + 2);
        }
    }

    // Epilogue: D col = lane&15, row = (lane>>4)*4 + reg. K-split partials
    // atomically accumulate onto bias-initialized out.
    {
        const int o = o0 + wv * 16 + l15;
        float* op = out + o;
#pragma unroll
        for (int r = 0; r < 4; ++r) {
            const int tr = lg * 4 + r;
            unsafeAtomicAdd(op + (size_t)(tr     ) * OUT_F, scale * acc0[r]);
            unsafeAtomicAdd(op + (size_t)(tr + 16) * OUT_F, scale * acc1[r]);
            unsafeAtomicAdd(op + (size_t)(tr + 32) * OUT_F, scale * acc2[r]);
            unsafeAtomicAdd(op + (size_t)(tr + 48) * OUT_F, scale * acc3[r]);
        }
    }
}

extern "C" void kernel_launch(void* const* d_in, const int* in_sizes, int n_in,
                              void* d_out, int out_size, void* d_ws, size_t ws_size,
                              hipStream_t stream) {
    const float* x     = (const float*)d_in[0];
    const int*   w     = (const int*)d_in[1];
    const float* scale = (const float*)d_in[2];
    const int*   zp    = (const int*)d_in[3];
    const float* bias  = (const float*)d_in[4];
    float*       out   = (float*)d_out;
    unsigned short* xbf = (unsigned short*)d_ws;   // 512 KB of d_ws

    prep<<<dim3(344), dim3(256), 0, stream>>>(x, bias, xbf, out);
    qlin11<<<dim3((OUT_F / COLS) * KSPLIT), dim3(512), 0, stream>>>(xbf, w, scale, zp, out);
}

// Round 12
// 48.930 us; speedup vs baseline: 1.3276x; 1.0099x over previous
//
#include <hip/hip_runtime.h>
#include <hip/hip_bf16.h>

typedef __attribute__((ext_vector_type(8))) short short8;
typedef __attribute__((ext_vector_type(4))) float f32x4;
typedef __attribute__((ext_vector_type(4))) int   int4v;

#define IN_F   4096
#define OUT_F  11008
#define COLS   128               // out-cols per block
#define KSPLIT 8
#define KPART  (IN_F / KSPLIT)   // 512 k per block
#define BK     64
#define NIT    (KPART / BK)      // 8 chunks
#define DEPTH  2                 // LDS ring slots (stage-ahead 1, vmcnt(5))

// f32 -> bf16 round-to-nearest-even
__device__ __forceinline__ short bf16_rne(float f) {
    unsigned u = __builtin_bit_cast(unsigned, f);
    u += 0x7FFFu + ((u >> 16) & 1u);
    return (short)(u >> 16);
}

__device__ __forceinline__ void gld16(const void* g, void* l) {
    __builtin_amdgcn_global_load_lds(
        (const __attribute__((address_space(1))) unsigned int*)g,
        (__attribute__((address_space(3))) unsigned int*)l,
        16, 0, 0);
}

// dequant 8 ints -> short8 bf16 (exact: values in [-3,123])
__device__ __forceinline__ short8 deq8(int4v q0, int4v q1, int zp) {
    short8 r;
#pragma unroll
    for (int j = 0; j < 4; ++j) {
        r[j]     = (short)(__builtin_bit_cast(unsigned, (float)(q0[j] - zp)) >> 16);
        r[j + 4] = (short)(__builtin_bit_cast(unsigned, (float)(q1[j] - zp)) >> 16);
    }
    return r;
}

// ---------- prep: X f32->bf16 cast (blocks 0..127) + bias-init of out (all) --
__global__ __launch_bounds__(256)
void prep(const float* __restrict__ x, const float* __restrict__ bias,
          unsigned short* __restrict__ xb, float* __restrict__ out) {
    const unsigned cid = blockIdx.x * 256 + threadIdx.x;
    if (blockIdx.x < 128) {
        const int i = cid * 8;
        f32x4 a = *(const f32x4*)(x + i);
        f32x4 b = *(const f32x4*)(x + i + 4);
        short8 o;
#pragma unroll
        for (int j = 0; j < 4; ++j) { o[j] = bf16_rne(a[j]); o[j + 4] = bf16_rne(b[j]); }
        *(short8*)(xb + i) = o;
    }
    const unsigned row = cid / (OUT_F / 8);
    const unsigned o   = (cid - row * (OUT_F / 8)) * 8;
    f32x4 b0 = *(const f32x4*)(bias + o);
    f32x4 b1 = *(const f32x4*)(bias + o + 4);
    float* dst = out + (size_t)row * OUT_F + o;
    *(f32x4*)dst = b0;
    *(f32x4*)(dst + 4) = b1;
}

// ---------- main GEMM: 128 cols x 64 tokens, 8 waves own 16-col slices -------
// Stage chunk IT into ring slot IT&1: W 128x64 int32 (32KB, 4 gld/thr),
// X 64x64 bf16 (8KB, 1 gld/thr). Sources pre-swizzled (chunk ^ row&7),
// LDS dest linear (rule #21). 5 vmem instr per wave per stage.
#define STAGE(IT) do {                                                        \
    const int _s = (IT) & (DEPTH - 1);                                        \
    const int* _wsi = wsrc + (size_t)(IT) * BK;                               \
    gld16(_wsi,             (char*)wt[_s] + tid * 16);                        \
    gld16(_wsi + 32 * IN_F, (char*)wt[_s] + 8192  + tid * 16);                \
    gld16(_wsi + 64 * IN_F, (char*)wt[_s] + 16384 + tid * 16);                \
    gld16(_wsi + 96 * IN_F, (char*)wt[_s] + 24576 + tid * 16);                \
    gld16(xsrc + (size_t)(IT) * BK, (char*)xt[_s] + tid * 16);                \
} while (0)

// One chunk (BK=64): dequant own 16-col W slice once (2 k-step B-frags),
// then 4 token-groups x 2 k-steps = 8 MFMA.
#define COMPUTE(S) do {                                                       \
    const char* _wb = (const char*)wt[S] + wrow_off;                          \
    int4v _q00 = *(const int4v*)(_wb + cw00);                                 \
    int4v _q01 = *(const int4v*)(_wb + cw01);                                 \
    int4v _q10 = *(const int4v*)(_wb + cw10);                                 \
    int4v _q11 = *(const int4v*)(_wb + cw11);                                 \
    short8 _B0 = deq8(_q00, _q01, zp);                                        \
    short8 _B1 = deq8(_q10, _q11, zp);                                        \
    const char* _xb = (const char*)xt[S] + arow;                              \
    short8 _a;                                                                \
    _a = *(const short8*)(_xb +        ca0);                                  \
    acc0 = __builtin_amdgcn_mfma_f32_16x16x32_bf16(_a, _B0, acc0, 0, 0, 0);   \
    _a = *(const short8*)(_xb +        ca1);                                  \
    acc0 = __builtin_amdgcn_mfma_f32_16x16x32_bf16(_a, _B1, acc0, 0, 0, 0);   \
    _a = *(const short8*)(_xb + 2048 + ca0);                                  \
    acc1 = __builtin_amdgcn_mfma_f32_16x16x32_bf16(_a, _B0, acc1, 0, 0, 0);   \
    _a = *(const short8*)(_xb + 2048 + ca1);                                  \
    acc1 = __builtin_amdgcn_mfma_f32_16x16x32_bf16(_a, _B1, acc1, 0, 0, 0);   \
    _a = *(const short8*)(_xb + 4096 + ca0);                                  \
    acc2 = __builtin_amdgcn_mfma_f32_16x16x32_bf16(_a, _B0, acc2, 0, 0, 0);   \
    _a = *(const short8*)(_xb + 4096 + ca1);                                  \
    acc2 = __builtin_amdgcn_mfma_f32_16x16x32_bf16(_a, _B1, acc2, 0, 0, 0);   \
    _a = *(const short8*)(_xb + 6144 + ca0);                                  \
    acc3 = __builtin_amdgcn_mfma_f32_16x16x32_bf16(_a, _B0, acc3, 0, 0, 0);   \
    _a = *(const short8*)(_xb + 6144 + ca1);                                  \
    acc3 = __builtin_amdgcn_mfma_f32_16x16x32_bf16(_a, _B1, acc3, 0, 0, 0);   \
} while (0)

__global__ __launch_bounds__(512, 4)
void qlin8(const unsigned short* __restrict__ xb, const int* __restrict__ w,
           const float* __restrict__ scale_p, const int* __restrict__ zp_p,
           float* __restrict__ out)
{
    __shared__ __align__(16) int            wt[DEPTH][COLS * BK]; // 2 x 32KB
    __shared__ __align__(16) unsigned short xt[DEPTH][64 * BK];   // 2 x 8KB  (80KB -> 2 blk/CU)

    const int tid  = threadIdx.x;
    const int lane = tid & 63;
    const int wv   = tid >> 6;      // wave 0..7 -> 16-col slice
    const int l15  = lane & 15;
    const int lg   = lane >> 4;

    const int ob = blockIdx.x >> 3;          // 86 col-tiles
    const int kh = blockIdx.x & 7;           // K eighth
    const int o0 = ob * COLS;
    const int kb = kh * KPART;

    const int   zp    = zp_p[0];
    const float scale = scale_p[0];

    // W staging: thread t -> rows (t>>4)+{0,32,64,96}, chunk (t&15)^(row&7).
    // (row+32k)&7 == row&7, so one swizzled base serves all 4 slices.
    const int wr = tid >> 4;                 // 0..31
    const int wc = (tid & 15) ^ (wr & 7);
    const int* wsrc = w + (size_t)(o0 + wr) * IN_F + kb + wc * 4;

    // X staging: thread t -> row t>>3 (0..63), chunk (t&7)^(row&7).
    const int xr = tid >> 3;
    const int xc = (tid & 7) ^ (xr & 7);
    const unsigned short* xsrc = xb + (size_t)xr * IN_F + kb + xc * 8;

    // Read-side swizzle: B row = wv*16+l15, A row = g*16+l15.
    const int rswz = l15 & 7;
    const int wrow_off = (wv * 16 + l15) * 256;          // W LDS row (256B pitch)
    const int cw00 = ((lg * 2    ) ^ rswz) * 16;
    const int cw01 = ((lg * 2 + 1) ^ rswz) * 16;
    const int cw10 = ((8 + lg * 2    ) ^ rswz) * 16;
    const int cw11 = ((8 + lg * 2 + 1) ^ rswz) * 16;
    const int arow = l15 * 128;                          // X LDS row (128B pitch)
    const int ca0  = ((lg    ) ^ rswz) * 16;
    const int ca1  = ((4 + lg) ^ rswz) * 16;

    f32x4 acc0 = {0.f, 0.f, 0.f, 0.f};
    f32x4 acc1 = {0.f, 0.f, 0.f, 0.f};
    f32x4 acc2 = {0.f, 0.f, 0.f, 0.f};
    f32x4 acc3 = {0.f, 0.f, 0.f, 0.f};

    // Prologue: 2 chunks in flight (10 vmem instrs/wave)
    STAGE(0);
    STAGE(1);

    // Window it: vmcnt(5) -> chunk it landed, chunk it+1 stays in flight;
    // barrier (cross-wave visibility); compute; barrier (seal slot it&1);
    // stage it+2 into slot it&1.
#pragma unroll
    for (int it = 0; it < NIT; ++it) {
        if (it < NIT - 1) asm volatile("s_waitcnt vmcnt(5)" ::: "memory");
        else              asm volatile("s_waitcnt vmcnt(0)" ::: "memory");
        __builtin_amdgcn_s_barrier();
        COMPUTE(it & 1);
        if (it + 2 < NIT) {
            __builtin_amdgcn_s_barrier();
            STAGE(it + 2);
        }
    }

    // Epilogue: D col = lane&15, row = (lane>>4)*4 + reg. K-split partials
    // atomically accumulate onto bias-initialized out.
    {
        const int o = o0 + wv * 16 + l15;
        float* op = out + o;
#pragma unroll
        for (int r = 0; r < 4; ++r) {
            const int tr = lg * 4 + r;
            unsafeAtomicAdd(op + (size_t)(tr     ) * OUT_F, scale * acc0[r]);
            unsafeAtomicAdd(op + (size_t)(tr + 16) * OUT_F, scale * acc1[r]);
            unsafeAtomicAdd(op + (size_t)(tr + 32) * OUT_F, scale * acc2[r]);
            unsafeAtomicAdd(op + (size_t)(tr + 48) * OUT_F, scale * acc3[r]);
        }
    }
}

extern "C" void kernel_launch(void* const* d_in, const int* in_sizes, int n_in,
                              void* d_out, int out_size, void* d_ws, size_t ws_size,
                              hipStream_t stream) {
    const float* x     = (const float*)d_in[0];
    const int*   w     = (const int*)d_in[1];
    const float* scale = (const float*)d_in[2];
    const int*   zp    = (const int*)d_in[3];
    const float* bias  = (const float*)d_in[4];
    float*       out   = (float*)d_out;
    unsigned short* xbf = (unsigned short*)d_ws;   // 512 KB of d_ws

    prep<<<dim3(344), dim3(256), 0, stream>>>(x, bias, xbf, out);
    qlin8<<<dim3((OUT_F / COLS) * KSPLIT), dim3(512), 0, stream>>>(xbf, w, scale, zp, out);
}